// Round 16
// baseline (74.621 us; speedup 1.0000x reference)
//
#include <hip/hip_runtime.h>

// HBV hydrological model, MI355X (gfx950).
// x (365,1000,3) f32, parameters (365,1000,14,16) f32, staind i32 -> out (365,1000,1) f32.
//
// Latency-bound sequential scan. Calibrated model (R5/R8/R12/R14/R15): lone-wave
// issue cadence ~8 cy/instr (351cy/44instr == R5's 694/88); dep stalls already
// hidden; wall time ~= instr_count x 8cy. Only remaining lever: fewer instructions.
// R16: 2 chains/lane (mu=ml, ml+8 of SAME g) as ext_vector float2 -- the ~36
// fma/mul/add ops per step-pair SLP-pack into v_pk_*_f32 (VOP3P), halving their
// issue count; min/max/med3/trans stay scalar (no pk variants). Expected ~39
// instr/chain-step vs ~56. Wave count 250->125 is irrelevant (wall-per-wave).
// Carried: R11 register banks, R12/R14 spine algebra, deferred mu-reduce, LDS out.

static constexpr int   NSTEP = 365;
static constexpr int   NGRID = 1000;
static constexpr int   MU    = 16;
static constexpr float PRECS = 1e-5f;
static constexpr int   QPAD  = 68;     // qlds row stride (words); rows 16B-aligned

typedef float v2 __attribute__((ext_vector_type(2)));

static __device__ __forceinline__ v2 v2min(v2 a, v2 b) {
    return (v2){fminf(a.x, b.x), fminf(a.y, b.y)};
}
static __device__ __forceinline__ v2 v2max(v2 a, v2 b) {
    return (v2){fmaxf(a.x, b.x), fmaxf(a.y, b.y)};
}
static __device__ __forceinline__ v2 v2med3(v2 a, v2 hi) {   // med3(a, 0, hi), hi>=0
    return (v2){__builtin_amdgcn_fmed3f(a.x, 0.0f, hi.x),
                __builtin_amdgcn_fmed3f(a.y, 0.0f, hi.y)};
}
static __device__ __forceinline__ v2 v2log(v2 a) {
    return (v2){__builtin_amdgcn_logf(a.x), __builtin_amdgcn_logf(a.y)};
}
static __device__ __forceinline__ v2 v2exp2(v2 a) {
    return (v2){__builtin_amdgcn_exp2f(a.x), __builtin_amdgcn_exp2f(a.y)};
}

__global__ __launch_bounds__(64)
__attribute__((amdgpu_waves_per_eu(1, 1)))
void hbv_kernel(const float* __restrict__ x,
                const float* __restrict__ par,
                const int*   __restrict__ staind_p,
                float*       __restrict__ out)
{
    __shared__ float qlds[NSTEP * QPAD];   // 99,280 B: per-lane pair-sum Q per step

    const int lane = threadIdx.x;          // 0..63
    const int ml   = lane & 7;             // chains: mu=ml and mu=ml+8
    const int gl   = lane >> 3;            // 0..7 local g
    const int gbase = blockIdx.x * 8;
    const int g    = gbase + gl;
    const int staind = *staind_p;

    const size_t tstride = (size_t)NGRID * 14 * MU;
    const int    xstride = NGRID * 3;
    const int    lp = g * (14 * MU) + ml;  // chain0 param offset; chain1 = +8
    const int    lx = g * 3;

    // ---- static params (both chains): parameters[staind, g, i, ml + {0,8}] ----
    const float* ps = par + (size_t)staind * tstride + lp;
#define LD2(i) ((v2){ps[(i)*MU], ps[(i)*MU + 8]})
    const v2 FC    = 50.0f  + LD2(1) * (1000.0f - 50.0f);
    const v2 K0    = 0.05f  + LD2(2) * (0.9f  - 0.05f);
    const v2 K1    = 0.01f  + LD2(3) * (0.5f  - 0.01f);
    const v2 K2    = 0.001f + LD2(4) * (0.2f  - 0.001f);
    const v2 LP    = 0.2f   + LD2(5) * (1.0f  - 0.2f);
    const v2 PERCp =          LD2(6) * 10.0f;
    const v2 UZL   =          LD2(7) * 100.0f;
    const v2 TT    = -2.5f  + LD2(8) * 5.0f;
    const v2 CFMAX = 0.5f   + LD2(9) * (10.0f - 0.5f);
    const v2 CRF   =          LD2(10) * 0.1f * CFMAX;
    const v2 CWH   =          LD2(11) * 0.2f;
    const v2 C     =          LD2(13);
#undef LD2
    const v2 rFC    = 1.0f / FC;
    const v2 lgFC   = v2log(FC);
    const v2 dlg    = lgFC - v2log(LP * FC);   // log2(1/LP) >= 0
    const v2 K1c    = 1.0f - K1;
    const v2 K2c    = 1.0f - K2;
    const v2 nK0UZL = -K0 * UZL;

    // ---- state (both chains) ----
    v2 SP = 1e-3f, MW = 1e-3f, SM = 1e-3f, SUZ = 1e-3f, SLZ = 1e-3f;

    auto step = [&](float P, float T, float E, v2 p0, v2 p12) -> float {
        // off-chain prep (packable fma/mul; selects scalar per component)
        const v2 BETA   = p0  * 5.0f + 1.0f;
        const v2 BETAET = p12 * 4.7f + 0.3f;
        const v2 dT     = T - TT;
        const v2 acap   = CFMAX * dT;
        const v2 bcap   = CRF * (-dT);
        v2 RAIN, SNOW;
        RAIN.x = (T >= TT.x) ? P : 0.0f;  SNOW.x = (T >= TT.x) ? 0.0f : P;
        RAIN.y = (T >= TT.y) ? P : 0.0f;  SNOW.y = (T >= TT.y) ? 0.0f : P;
        const v2 smsuz  = SUZ + SM;

        // snow module
        const v2 SP1  = SP + SNOW;
        const v2 melt = v2med3(acap, SP1);         // med3(acap, 0, SP1), SP1 >= 0
        const v2 SP2  = SP1 - melt;
        const v2 MW1  = MW + melt;
        const v2 refr = v2med3(bcap, MW1);         // med3(bcap, 0, MW1), MW1 >= 0
        const v2 MW2  = MW1 - refr;
        const v2 SP3  = SP2 + refr;
        const v2 lim  = CWH * SP3;
        const v2 tosoil = v2max(MW2 - lim, (v2)0.0f);
        SP = SP3;
        MW = v2min(MW2, lim);                      // MW2 - tosoil (exact)

        // soil module -- shared log-domain clamp for both pows
        const v2 SM1   = v2min(SM, FC);
        const v2 SUZe  = smsuz - SM1;              // SUZ + excess
        const v2 lg    = v2log(SM);                // SM >= PRECS
        const v2 uc    = v2min(lg - lgFC, (v2)0.0f);
        const v2 wet   = v2exp2(BETA * uc);
        const v2 evapf = v2exp2(BETAET * v2min(uc + dlg, (v2)0.0f));
        const v2 SM2   = v2max(SM1 - E * evapf, (v2)PRECS);
        const v2 rt    = RAIN + tosoil;
        const v2 recharge = rt * wet;
        const v2 SM3   = (SM2 + rt) - recharge;
        const v2 capf  = v2max(1.0f - SM3 * rFC, (v2)0.0f);
        const v2 cap   = (C * SLZ) * capf;         // min(SLZ,.) never binds: C,capf<=1
        SM = v2max(SM3 + cap, (v2)PRECS);
        const v2 SLZ1  = v2max(SLZ - cap, (v2)PRECS);

        // response (PERC and SUZ2 parallel off SUZ1)
        const v2 SUZ1 = SUZe + recharge;
        const v2 PERC = v2min(SUZ1, PERCp);
        const v2 SUZ2 = v2max(SUZ1 - PERCp, (v2)0.0f);
        const v2 Q0   = v2max(K0 * SUZ2 + nK0UZL, (v2)0.0f);
        const v2 SUZ3 = SUZ2 - Q0;
        const v2 Q1   = K1 * SUZ3;
        SUZ = K1c * SUZ3;
        const v2 SLZ2 = SLZ1 + PERC;
        const v2 Q2   = K2 * SLZ2;
        SLZ = K2c * SLZ2;

        const v2 q = Q0 + Q1 + Q2;
        return q.x + q.y;                          // in-lane pair sum (2 of 16 mu)
    };

    // ---- double-buffered register banks (statically indexed via macros) ----
    float aP[10], aT[10], aE[10];
    v2    a0[10], a12[10];
    float cP[10], cT[10], cE[10];
    v2    c0[10], c12[10];
    const float* prow = par;   // uniform step-row base, advances tstride per row
    const float* xrow = x;     // uniform step-row base, advances xstride per row

#define LOADB(BP, BT, BE, B0, B12, N)                                 \
    _Pragma("unroll") for (int j = 0; j < (N); ++j) {                 \
        B0[j]  = (v2){prow[lp],       prow[lp + 8]};                  \
        B12[j] = (v2){prow[lp + 192], prow[lp + 200]};                \
        const float3 v = *(const float3*)(xrow + lx);                 \
        BP[j] = v.x; BT[j] = v.y; BE[j] = v.z;                        \
        prow += tstride; xrow += xstride;                             \
    }

#define COMPB(BP, BT, BE, B0, B12, T0, N)                             \
    {                                                                 \
        float qreg[10];                                               \
        _Pragma("unroll") for (int j = 0; j < (N); ++j)               \
            qreg[j] = step(BP[j], BT[j], BE[j], B0[j], B12[j]);       \
        _Pragma("unroll") for (int j = 0; j < (N); ++j)               \
            qlds[((T0) + j) * QPAD + lane] = qreg[j];                 \
    }

    LOADB(aP, aT, aE, a0, a12, 10)             // rows 0..9

    for (int bb = 0; bb < 17; ++bb) {          // 17 double-blocks = steps 0..339
        const int t0 = bb * 20;
        LOADB(cP, cT, cE, c0, c12, 10)         // rows t0+10 .. t0+19
        COMPB(aP, aT, aE, a0, a12, t0, 10)     // steps t0 .. t0+9 (pure ALU)
        LOADB(aP, aT, aE, a0, a12, 10)         // rows t0+20 .. t0+29
        COMPB(cP, cT, cE, c0, c12, t0 + 10, 10)
    }
    // invariant: bank a holds rows 340..349, prow at row 350

    LOADB(cP, cT, cE, c0, c12, 10)             // rows 350..359
    COMPB(aP, aT, aE, a0, a12, 340, 10)        // steps 340..349
    LOADB(aP, aT, aE, a0, a12, 5)              // rows 360..364
    COMPB(cP, cT, cE, c0, c12, 350, 10)        // steps 350..359
    COMPB(aP, aT, aE, a0, a12, 360, 5)         // steps 360..364

#undef LOADB
#undef COMPB

    // ---- flush: per output (t,gg) sum 8 lane pair-sums (= 16 mu), coalesced ----
    //      (1 wave/block, no barrier; rows 16B-aligned: t*272B + gg*32B)
    for (int i = lane; i < NSTEP * 8; i += 64) {
        const int t  = i >> 3;
        const int gg = i & 7;
        const float4* row = (const float4*)&qlds[t * QPAD + gg * 8];
        const float4 r0 = row[0], r1 = row[1];
        const float s0 = (r0.x + r0.y) + (r0.z + r0.w);
        const float s1 = (r1.x + r1.y) + (r1.z + r1.w);
        out[t * NGRID + gbase + gg] = (s0 + s1) * 0.0625f;
    }
}

extern "C" void kernel_launch(void* const* d_in, const int* in_sizes, int n_in,
                              void* d_out, int out_size, void* d_ws, size_t ws_size,
                              hipStream_t stream) {
    const float* x      = (const float*)d_in[0];
    const float* par    = (const float*)d_in[1];
    const int*   staind = (const int*)d_in[2];
    float*       out    = (float*)d_out;

    hipLaunchKernelGGL(hbv_kernel, dim3(NGRID / 8), dim3(64), 0, stream,
                       x, par, staind, out);
}

// Round 17
// 53.329 us; speedup vs baseline: 1.3993x; 1.3993x over previous
//
#include <hip/hip_runtime.h>

// HBV hydrological model, MI355X (gfx950) -- FINAL (R14 revert, best measured: 53.4us).
// x (365,1000,3) f32, parameters (365,1000,14,16) f32, staind i32 -> out (365,1000,1) f32.
//
// Latency-bound sequential scan: 16000 independent (g,mu) chains, 250 waves, 1 wave/CU.
// Measured ceiling model (calibrated R5/R8/R12/R14/R16 at three instruction counts):
// lone-wave issue/dep cadence ~8 cy/instr; wall = 365 steps x ~44 instr x ~8cy ~= 53us.
// No pipe saturated (HBM 1.3%, VALU ~12%); all stall-mechanism theories (store drain,
// vmcnt, scheduling, occupancy target, emission order) tested and falsified; both
// multi-chain-per-lane layouts (scalar R5, packed-f32 R16) regress. Instruction
// deletion was the only lever that moved time; R15's further trims were flat.
//
// Structure: 1 chain/lane; 20-step double-buffered register banks (loads batched at
// block boundaries); single-log pow algebra (1 v_log + 2 v_exp2 per step, shared
// log-domain clamp); med3 clamps; spine-minimal algebra (cap-min proven never binding,
// Q0 fma-fold, excess elimination, decay-mul state updates); per-lane Q to padded LDS,
// mu-reduction deferred to a single coalesced flush.

static constexpr int   NSTEP = 365;
static constexpr int   NGRID = 1000;
static constexpr int   MU    = 16;
static constexpr float PRECS = 1e-5f;
static constexpr int   QPAD  = 68;     // qlds row stride (words): 64 + 4 pad

__global__ __launch_bounds__(64)
__attribute__((amdgpu_waves_per_eu(1, 1)))
void hbv_kernel(const float* __restrict__ x,
                const float* __restrict__ par,
                const int*   __restrict__ staind_p,
                float*       __restrict__ out)
{
    __shared__ float qlds[NSTEP * QPAD];   // 99,280 B: per-lane Q per step

    const int lane = threadIdx.x;          // 0..63
    const int m    = lane & 15;            // mu index
    const int gl   = lane >> 4;            // 0..3 local g
    const int gbase = blockIdx.x * 4;
    const int g    = gbase + gl;
    const int staind = *staind_p;

    const size_t tstride = (size_t)NGRID * 14 * MU;
    const int    xstride = NGRID * 3;
    const int    lp = g * (14 * MU) + m;   // per-lane param offset within a step row
    const int    lx = g * 3;               // per-lane x offset within a step row

    // ---- static params: parameters[staind, g, i, m] ----
    const float* ps = par + (size_t)staind * tstride + lp;
    const float FC    = 50.0f  + ps[ 1*MU] * (1000.0f - 50.0f);
    const float K0    = 0.05f  + ps[ 2*MU] * (0.9f  - 0.05f);
    const float K1    = 0.01f  + ps[ 3*MU] * (0.5f  - 0.01f);
    const float K2    = 0.001f + ps[ 4*MU] * (0.2f  - 0.001f);
    const float LP    = 0.2f   + ps[ 5*MU] * (1.0f  - 0.2f);
    const float PERCp =          ps[ 6*MU] * 10.0f;
    const float UZL   =          ps[ 7*MU] * 100.0f;
    const float TT    = -2.5f  + ps[ 8*MU] * 5.0f;
    const float CFMAX = 0.5f   + ps[ 9*MU] * (10.0f - 0.5f);
    const float CRF   =          ps[10*MU] * 0.1f * CFMAX;
    const float CWH   =          ps[11*MU] * 0.2f;
    const float C     =          ps[13*MU] * 1.0f;
    const float rFC   = 1.0f / FC;
    const float lgFC   = __builtin_amdgcn_logf(FC);
    const float dlg    = lgFC - __builtin_amdgcn_logf(LP * FC);  // log2(1/LP) >= 0
    const float K1c    = 1.0f - K1;
    const float K2c    = 1.0f - K2;
    const float nK0UZL = -K0 * UZL;

    // ---- state ----
    float SP = 1e-3f, MW = 1e-3f, SM = 1e-3f, SUZ = 1e-3f, SLZ = 1e-3f;

    auto step = [&](float P, float T, float E, float p0, float p12) -> float {
        // off-chain prep
        const float BETA    = fmaf(p0, 5.0f, 1.0f);
        const float BETAET  = fmaf(p12, 4.7f, 0.3f);
        const float dT      = T - TT;
        const float acap    = CFMAX * dT;        // raw; med3 clamps
        const float bcap    = CRF * (-dT);       // raw; med3 clamps
        const bool  rc      = (T >= TT);
        const float RAIN    = rc ? P : 0.0f;
        const float SNOW    = rc ? 0.0f : P;
        const float smsuz   = SUZ + SM;          // for SUZe (excess eliminated)

        // snow module (SP, MW)
        const float SP1  = SP + SNOW;
        const float melt = __builtin_amdgcn_fmed3f(acap, 0.0f, SP1);  // SP1 >= 0
        const float SP2  = SP1 - melt;
        const float MW1  = MW + melt;
        const float refr = __builtin_amdgcn_fmed3f(bcap, 0.0f, MW1);  // MW1 >= 0
        const float MW2  = MW1 - refr;
        const float SP3  = SP2 + refr;
        const float lim  = CWH * SP3;
        const float tosoil = fmaxf(MW2 - lim, 0.0f);
        SP = SP3;
        MW = fminf(MW2, lim);                    // MW2 - tosoil (exact)

        // soil module -- shared log-domain clamp for both pows
        const float SM1    = fminf(SM, FC);            // SM - excess (exact)
        const float SUZe   = smsuz - SM1;              // SUZ + excess (ulp-level)
        const float lg     = __builtin_amdgcn_logf(SM);        // log2(SM), SM >= PRECS
        const float uc     = fminf(lg - lgFC, 0.0f);           // min(log2(SM/FC), 0)
        const float wet    = __builtin_amdgcn_exp2f(BETA * uc);
        const float evapf  = __builtin_amdgcn_exp2f(BETAET * fminf(uc + dlg, 0.0f));
        const float SM2    = fmaxf(fmaf(-E, evapf, SM1), PRECS);  // ETact fold (exact)
        const float rt     = RAIN + tosoil;
        const float recharge = rt * wet;
        const float SM3    = (SM2 + rt) - recharge;
        const float capf   = fmaxf(fmaf(-SM3, rFC, 1.0f), 0.0f);
        const float cap    = (C * SLZ) * capf;   // min(SLZ, .) never binds: C,capf <= 1
        SM = fmaxf(SM3 + cap, PRECS);
        const float SLZ1   = fmaxf(SLZ - cap, PRECS);

        // response
        const float SUZ1 = SUZe + recharge;
        const float PERC = fminf(SUZ1, PERCp);
        const float SUZ2 = SUZ1 - PERC;
        const float Q0   = fmaxf(fmaf(K0, SUZ2, nK0UZL), 0.0f);   // K0*max(SUZ2-UZL,0)
        const float SUZ3 = SUZ2 - Q0;
        const float Q1   = K1 * SUZ3;     // independent pair:
        SUZ = K1c * SUZ3;                 // SUZ3 - Q1 (ulp-level)
        const float SLZ2 = SLZ1 + PERC;
        const float Q2   = K2 * SLZ2;     // independent pair:
        SLZ = K2c * SLZ2;                 // SLZ2 - Q2 (ulp-level)

        return Q0 + Q1 + Q2;
    };

    // ---- double-buffered register banks (all statically indexed via macros) ----
    float aP[10], aT[10], aE[10], a0[10], a12[10];
    float cP[10], cT[10], cE[10], c0[10], c12[10];
    const float* prow = par;   // uniform step-row base, advances tstride per row
    const float* xrow = x;     // uniform step-row base, advances xstride per row

#define LOADB(BP, BT, BE, B0, B12, N)                            \
    _Pragma("unroll") for (int j = 0; j < (N); ++j) {            \
        B0[j]  = prow[lp];                                       \
        B12[j] = prow[lp + 192];                                 \
        const float3 v = *(const float3*)(xrow + lx);            \
        BP[j] = v.x; BT[j] = v.y; BE[j] = v.z;                   \
        prow += tstride; xrow += xstride;                        \
    }

#define COMPB(BP, BT, BE, B0, B12, T0, N)                        \
    {                                                            \
        float qreg[10];                                          \
        _Pragma("unroll") for (int j = 0; j < (N); ++j)          \
            qreg[j] = step(BP[j], BT[j], BE[j], B0[j], B12[j]);  \
        _Pragma("unroll") for (int j = 0; j < (N); ++j)          \
            qlds[((T0) + j) * QPAD + lane] = qreg[j];            \
    }

    LOADB(aP, aT, aE, a0, a12, 10)             // rows 0..9

    for (int bb = 0; bb < 17; ++bb) {          // 17 double-blocks = steps 0..339
        const int t0 = bb * 20;
        LOADB(cP, cT, cE, c0, c12, 10)         // rows t0+10 .. t0+19
        COMPB(aP, aT, aE, a0, a12, t0, 10)     // steps t0 .. t0+9 (pure ALU)
        LOADB(aP, aT, aE, a0, a12, 10)         // rows t0+20 .. t0+29
        COMPB(cP, cT, cE, c0, c12, t0 + 10, 10)
    }
    // invariant: bank a holds rows 340..349, prow at row 350

    LOADB(cP, cT, cE, c0, c12, 10)             // rows 350..359
    COMPB(aP, aT, aE, a0, a12, 340, 10)        // steps 340..349
    LOADB(aP, aT, aE, a0, a12, 5)              // rows 360..364
    COMPB(cP, cT, cE, c0, c12, 350, 10)        // steps 350..359
    COMPB(aP, aT, aE, a0, a12, 360, 5)         // steps 360..364

#undef LOADB
#undef COMPB

    // ---- flush: 16-lane sums + coalesced global stores (1 wave/block, no barrier;
    //      compiler inserts the lgkmcnt wait before the LDS reads) ----
    for (int i = lane; i < NSTEP * 4; i += 64) {
        const int t  = i >> 2;
        const int gg = i & 3;
        const float* row = &qlds[t * QPAD + gg * 16];
        float s = 0.0f;
#pragma unroll
        for (int k = 0; k < 16; ++k) s += row[k];
        out[t * NGRID + gbase + gg] = s * 0.0625f;
    }
}

extern "C" void kernel_launch(void* const* d_in, const int* in_sizes, int n_in,
                              void* d_out, int out_size, void* d_ws, size_t ws_size,
                              hipStream_t stream) {
    const float* x      = (const float*)d_in[0];
    const float* par    = (const float*)d_in[1];
    const int*   staind = (const int*)d_in[2];
    float*       out    = (float*)d_out;

    hipLaunchKernelGGL(hbv_kernel, dim3(NGRID / 4), dim3(64), 0, stream,
                       x, par, staind, out);
}